// Round 7
// baseline (297.873 us; speedup 1.0000x reference)
//
#include <hip/hip_runtime.h>
#include <stdint.h>

static constexpr int N = 2048;
static constexpr int B = 2;
static constexpr int T = 3;
static constexpr int H = 4;
static constexpr int D = 16;
static constexpr float NEG = -1e30f;
static constexpr float LOG2E = 1.4426950408889634f;

// ---- fused: pack graph bits (blocks [0,16384)) + h1 projection (rest) ----
__global__ void k_prep(const float* __restrict__ g, unsigned long long* __restrict__ mb,
                       const float* __restrict__ fx, const float* __restrict__ W1,
                       float* __restrict__ h1) {
    if (blockIdx.x < (unsigned)(N * N / 256)) {
        int idx = blockIdx.x * 256 + threadIdx.x;        // over N*N
        float v = g[idx];
        unsigned long long bal = __ballot(v != 0.0f);
        if ((threadIdx.x & 63) == 0) mb[idx >> 6] = bal;
        return;
    }
    int id = (blockIdx.x - N * N / 256) * 256 + threadIdx.x;   // T*B*H*N threads
    int n = id & (N - 1);
    int head = id >> 11;                                 // (t*B+b)*H+h
    int t = head >> 3;
    int b = (head >> 2) & 1;
    int h = head & 3;
    const float* f = fx + (((size_t)(b * N + n)) * T + t) * D;
    const float* w = W1 + ((t * H + h) * D) * (size_t)D;
    float fr[D];
    const float4* f4 = (const float4*)f;
#pragma unroll
    for (int k = 0; k < 4; ++k) {
        float4 v = f4[k];
        fr[4*k] = v.x; fr[4*k+1] = v.y; fr[4*k+2] = v.z; fr[4*k+3] = v.w;
    }
    float acc[D] = {};
#pragma unroll
    for (int c = 0; c < D; ++c)
#pragma unroll
        for (int d = 0; d < D; ++d) acc[d] = fmaf(fr[c], w[c*D+d], acc[d]);
    float* o = h1 + (size_t)id * D;
#pragma unroll
    for (int d = 0; d < D; ++d) o[d] = acc[d];
}

// ================= inner loop: online softmax, defer-max (THR=64, exp2 domain)
// hi pre-scaled by LOG2E. Masked j: se=NEG -> wg=exp2(NEG-m)=0 once m finite;
// all-masked prefix self-corrects at first rescale (cc=exp2(NEG-s)=0).
__device__ __forceinline__ void attn_slice(
        const float* __restrict__ hh, const uint32_t* __restrict__ mrow,
        const float (&hi)[D], int j0, int jlen,
        float& m, float& l, float (&o)[D]) {
    for (int w = 0; w < jlen/32; ++w) {
        uint32_t mw = mrow[w];
        const float* __restrict__ tb = hh + (size_t)(j0 + w*32) * D;
#pragma unroll 8
        for (int u = 0; u < 32; ++u) {
            const float4* h4 = (const float4*)(tb + u*D);
            float4 v0 = h4[0], v1 = h4[1], v2 = h4[2], v3 = h4[3];
            float hj[D];
            hj[0]=v0.x; hj[1]=v0.y; hj[2]=v0.z; hj[3]=v0.w;
            hj[4]=v1.x; hj[5]=v1.y; hj[6]=v1.z; hj[7]=v1.w;
            hj[8]=v2.x; hj[9]=v2.y; hj[10]=v2.z; hj[11]=v2.w;
            hj[12]=v3.x; hj[13]=v3.y; hj[14]=v3.z; hj[15]=v3.w;
            float s0=0.f, s1=0.f, s2=0.f, s3=0.f;
#pragma unroll
            for (int k = 0; k < 4; ++k) {
                s0 = fmaf(hi[k],    hj[k],    s0);
                s1 = fmaf(hi[k+4],  hj[k+4],  s1);
                s2 = fmaf(hi[k+8],  hj[k+8],  s2);
                s3 = fmaf(hi[k+12], hj[k+12], s3);
            }
            float s = (s0 + s1) + (s2 + s3);
            float se = (mw & (1u << u)) ? s : NEG;
            if (__any(se - m > 64.f)) {            // wave-rare: records by margin >64
                float mn = fmaxf(m, se);
                float cc = __builtin_amdgcn_exp2f(m - mn);
                l *= cc;
#pragma unroll
                for (int p = 0; p < D; ++p) o[p] *= cc;
                m = mn;
            }
            float wg = __builtin_amdgcn_exp2f(se - m);   // <= 2^64, fp32-safe
            l += wg;
#pragma unroll
            for (int k = 0; k < D; ++k) o[k] = fmaf(wg, hj[k], o[k]);
        }
    }
}

// load hi row, pre-scaled by LOG2E
__device__ __forceinline__ void load_hi(const float* __restrict__ hh, int row, float (&hi)[D]) {
    const float4* r4 = (const float4*)(hh + (size_t)row * D);
#pragma unroll
    for (int k = 0; k < 4; ++k) {
        float4 v = r4[k];
        hi[4*k]   = v.x * LOG2E;
        hi[4*k+1] = v.y * LOG2E;
        hi[4*k+2] = v.z * LOG2E;
        hi[4*k+3] = v.w * LOG2E;
    }
}

// LDS merge of SPLIT wave-partials -> lane r (threadIdx.x<64) returns (M,L,O)
template<int SPLIT>
__device__ __forceinline__ bool block_merge(
        int lane, int wv, float m, float l, const float (&o)[D],
        float& M, float& L, float (&O)[D]) {
    __shared__ float sm[SPLIT][64];
    __shared__ float sl[SPLIT][64];
    __shared__ float so[SPLIT][64][D+1];
    sm[wv][lane] = m;
    sl[wv][lane] = l;
#pragma unroll
    for (int k = 0; k < D; ++k) so[wv][lane][k] = o[k];
    __syncthreads();
    if (threadIdx.x >= 64) return false;
    int r = threadIdx.x;
    M = sm[0][r];
#pragma unroll
    for (int s = 1; s < SPLIT; ++s) M = fmaxf(M, sm[s][r]);
    L = 0.f;
#pragma unroll
    for (int k = 0; k < D; ++k) O[k] = 0.f;
#pragma unroll
    for (int s = 0; s < SPLIT; ++s) {
        float cc = __builtin_amdgcn_exp2f(sm[s][r] - M);
        L = fmaf(cc, sl[s][r], L);
#pragma unroll
        for (int k = 0; k < D; ++k) O[k] = fmaf(cc, so[s][r][k], O[k]);
    }
    return true;
}

// ---- partial attention: j split across waves AND grid-z blocks ----
template<int SPLIT, int JS>
__global__ __launch_bounds__(64*SPLIT) void attn_p(
        const float* __restrict__ hsrc, const uint32_t* __restrict__ mask,
        float* __restrict__ pm, float* __restrict__ pl, float* __restrict__ po) {
    constexpr int JLEN = N / (SPLIT * JS);
    static_assert(JLEN >= 32, "mask-word floor");
    const int lane = threadIdx.x & 63;
    const int wv = threadIdx.x >> 6;
    const int row = blockIdx.x * 64 + lane;
    const int head = blockIdx.y;
    const int js = blockIdx.z;
    const float* __restrict__ hh = hsrc + (size_t)head * N * D;

    float hi[D];
    load_hi(hh, row, hi);
    const int j0 = __builtin_amdgcn_readfirstlane((js * SPLIT + wv) * JLEN);
    const uint32_t* __restrict__ mrow = mask + (size_t)row * (N/32) + (j0 >> 5);
    float m = NEG, l = 0.f, o[D] = {};
    attn_slice(hh, mrow, hi, j0, JLEN, m, l, o);

    float M, L, O[D];
    if (block_merge<SPLIT>(lane, wv, m, l, o, M, L, O)) {
        int rr = blockIdx.x * 64 + threadIdx.x;
        size_t pidx = ((size_t)head * N + rr) * JS + js;
        pm[pidx] = M;
        pl[pidx] = L;
#pragma unroll
        for (int k = 0; k < D; ++k) po[pidx * D + k] = O[k];
    }
}

// ---- fused: merge layer-1 partials (4 heads) + leaky + x2@W2 -> h2 ----
// thread = ((t*B+b)*N+row)*4 + q ; q = output quarter
template<int JS>
__global__ void k_mr1(const float* __restrict__ pm, const float* __restrict__ pl,
                      const float* __restrict__ po, const float* __restrict__ b1,
                      const float* __restrict__ W2, float* __restrict__ h2) {
    int id = blockIdx.x * 256 + threadIdx.x;
    int q = id & 3;
    int tbrow = id >> 2;                 // (t*B+b)*N + row
    int row = tbrow & (N - 1);
    int tb = tbrow >> 11;                // t*B+b
    int t = tb >> 1;
    float x2[H * D];
#pragma unroll
    for (int hd = 0; hd < H; ++hd) {
        size_t base = ((size_t)(tb * H + hd) * N + row) * JS;
        float M = pm[base];
#pragma unroll
        for (int s = 1; s < JS; ++s) M = fmaxf(M, pm[base + s]);
        float L = 0.f, O[D] = {};
#pragma unroll
        for (int s = 0; s < JS; ++s) {
            float cc = __builtin_amdgcn_exp2f(pm[base + s] - M);
            L = fmaf(cc, pl[base + s], L);
            const float4* pp = (const float4*)(po + (base + s) * D);
#pragma unroll
            for (int k4 = 0; k4 < 4; ++k4) {
                float4 v = pp[k4];
                O[4*k4]   = fmaf(cc, v.x, O[4*k4]);
                O[4*k4+1] = fmaf(cc, v.y, O[4*k4+1]);
                O[4*k4+2] = fmaf(cc, v.z, O[4*k4+2]);
                O[4*k4+3] = fmaf(cc, v.w, O[4*k4+3]);
            }
        }
        float inv = 1.0f / L;
        const float* bb = b1 + (t * H + hd) * D;
#pragma unroll
        for (int k = 0; k < D; ++k) {
            float v = fmaf(O[k], inv, bb[k]);
            x2[hd * D + k] = (v > 0.f) ? v : 0.01f * v;   // leaky
        }
    }
    const float* w = W2 + (size_t)t * (H * D) * D + q * 4;
    float acc[4] = {};
#pragma unroll
    for (int c = 0; c < H * D; ++c)
#pragma unroll
        for (int d = 0; d < 4; ++d) acc[d] = fmaf(x2[c], w[c * D + d], acc[d]);
    float* outp = h2 + (size_t)tbrow * D + q * 4;
#pragma unroll
    for (int d = 0; d < 4; ++d) outp[d] = acc[d];
}

// ---- fused: merge layer-2 partials (3 t's) + leaky + hidden@W3 -> h3 ----
// thread = (b*N+row)*4 + q
template<int JS>
__global__ void k_mr2(const float* __restrict__ pm, const float* __restrict__ pl,
                      const float* __restrict__ po, const float* __restrict__ b2,
                      const float* __restrict__ W3, float* __restrict__ h3) {
    int id = blockIdx.x * 256 + threadIdx.x;
    int q = id & 3;
    int brow = id >> 2;                  // b*N + row
    int row = brow & (N - 1);
    int b = brow >> 11;
    float hid[T * D];
#pragma unroll
    for (int t = 0; t < T; ++t) {
        size_t base = ((size_t)(t * B + b) * N + row) * JS;
        float M = pm[base];
#pragma unroll
        for (int s = 1; s < JS; ++s) M = fmaxf(M, pm[base + s]);
        float L = 0.f, O[D] = {};
#pragma unroll
        for (int s = 0; s < JS; ++s) {
            float cc = __builtin_amdgcn_exp2f(pm[base + s] - M);
            L = fmaf(cc, pl[base + s], L);
            const float4* pp = (const float4*)(po + (base + s) * D);
#pragma unroll
            for (int k4 = 0; k4 < 4; ++k4) {
                float4 v = pp[k4];
                O[4*k4]   = fmaf(cc, v.x, O[4*k4]);
                O[4*k4+1] = fmaf(cc, v.y, O[4*k4+1]);
                O[4*k4+2] = fmaf(cc, v.z, O[4*k4+2]);
                O[4*k4+3] = fmaf(cc, v.w, O[4*k4+3]);
            }
        }
        float inv = 1.0f / L;
        const float* bb = b2 + t * D;
#pragma unroll
        for (int k = 0; k < D; ++k) {
            float v = fmaf(O[k], inv, bb[k]);
            hid[t * D + k] = (v > 0.f) ? v : 0.01f * v;   // leaky
        }
    }
    const float* w = W3 + q * 4;         // W3 [48][16]
    float acc[4] = {};
#pragma unroll
    for (int c = 0; c < T * D; ++c)
#pragma unroll
        for (int d = 0; d < 4; ++d) acc[d] = fmaf(hid[c], w[c * D + d], acc[d]);
    float* outp = h3 + (size_t)brow * D + q * 4;
#pragma unroll
    for (int d = 0; d < 4; ++d) outp[d] = acc[d];
}

// ---- merge layer-3 partials, apply bias, write final out ----
template<int JS>
__global__ void k_merge3(const float* __restrict__ pm, const float* __restrict__ pl,
                         const float* __restrict__ po, const float* __restrict__ bias,
                         float* __restrict__ out) {
    int id = blockIdx.x * 256 + threadIdx.x;             // b*N + row
    size_t base = (size_t)id * JS;
    float M = pm[base];
#pragma unroll
    for (int s = 1; s < JS; ++s) M = fmaxf(M, pm[base + s]);
    float L = 0.f, O[D] = {};
#pragma unroll
    for (int s = 0; s < JS; ++s) {
        float cc = __builtin_amdgcn_exp2f(pm[base + s] - M);
        L = fmaf(cc, pl[base + s], L);
        const float* pp = po + (base + s) * D;
#pragma unroll
        for (int k = 0; k < D; ++k) O[k] = fmaf(cc, pp[k], O[k]);
    }
    float inv = 1.0f / L;
    float* orow = out + (size_t)id * D;
#pragma unroll
    for (int k = 0; k < D; ++k) orow[k] = fmaf(O[k], inv, bias[k]);
}

template<int JS1>
static void run_pipeline(const float* graph, const float* fx,
                         const float* W1, const float* b1, const float* W2,
                         const float* b2, const float* W3, const float* b3,
                         float* out, unsigned long long* mask64, float* h1,
                         float* h2, float* h3, float* pm, float* pl, float* po,
                         hipStream_t stream) {
    const uint32_t* mk = (const uint32_t*)mask64;
    k_prep<<<N*N/256 + T*B*H*N/256, 256, 0, stream>>>(graph, mask64, fx, W1, h1);
    attn_p<4,JS1><<<dim3(N/64, T*B*H, JS1), 256, 0, stream>>>(h1, mk, pm, pl, po);
    k_mr1<JS1><<<T*B*N*4/256, 256, 0, stream>>>(pm, pl, po, b1, W2, h2);
    attn_p<4,8><<<dim3(N/64, T*B, 8), 256, 0, stream>>>(h2, mk, pm, pl, po);
    k_mr2<8><<<B*N*4/256, 256, 0, stream>>>(pm, pl, po, b2, W3, h3);
    attn_p<4,16><<<dim3(N/64, B, 16), 256, 0, stream>>>(h3, mk, pm, pl, po);
    k_merge3<16><<<B*N/256, 256, 0, stream>>>(pm, pl, po, b3, out);
}

extern "C" void kernel_launch(void* const* d_in, const int* in_sizes, int n_in,
                              void* d_out, int out_size, void* d_ws, size_t ws_size,
                              hipStream_t stream) {
    const float* fx    = (const float*)d_in[0];
    const float* graph = (const float*)d_in[1];
    const float* W1    = (const float*)d_in[2];
    const float* b1    = (const float*)d_in[3];
    const float* W2    = (const float*)d_in[4];
    const float* b2    = (const float*)d_in[5];
    const float* W3    = (const float*)d_in[6];
    const float* b3    = (const float*)d_in[7];
    float* out = (float*)d_out;

    char* ws = (char*)d_ws;
    unsigned long long* mask64 = (unsigned long long*)ws;            // 512 KB
    float* h1 = (float*)(ws + (size_t)(N*(size_t)N/8));              // [24][N][16] 3MB
    float* h2 = h1 + (size_t)T*B*H*N*D;                              // [T][B][N][16]
    float* h3 = h2 + (size_t)T*B*N*D;                                // [B][N][16]
    float* tail = h3 + (size_t)B*N*D;

    // layer-1 partial counts per JS tier (layer-2/3 needs are strictly smaller)
    constexpr size_t P8 = (size_t)T*B*H*N*8;
    constexpr size_t P4 = (size_t)T*B*H*N*4;
    constexpr size_t P2 = (size_t)T*B*H*N*2;
    size_t need8 = (char*)(tail + P8*(2 + D)) - ws;
    size_t need4 = (char*)(tail + P4*(2 + D)) - ws;

    if (ws_size >= need8) {
        float *pm = tail, *pl = tail + P8, *po = tail + 2*P8;
        run_pipeline<8>(graph, fx, W1, b1, W2, b2, W3, b3, out,
                        mask64, h1, h2, h3, pm, pl, po, stream);
    } else if (ws_size >= need4) {
        float *pm = tail, *pl = tail + P4, *po = tail + 2*P4;
        run_pipeline<4>(graph, fx, W1, b1, W2, b2, W3, b3, out,
                        mask64, h1, h2, h3, pm, pl, po, stream);
    } else {
        float *pm = tail, *pl = tail + P2, *po = tail + 2*P2;
        run_pipeline<2>(graph, fx, W1, b1, W2, b2, W3, b3, out,
                        mask64, h1, h2, h3, pm, pl, po, stream);
    }
}